// Round 7
// baseline (103.951 us; speedup 1.0000x reference)
//
#include <hip/hip_runtime.h>
#include <math.h>

#define N      128
#define NS     16
#define NC     4
#define NT     4
#define NPIX   (N * N)       // 16384

// cis(2*pi*rev) via libm sincosf on a range-reduced radian argument.
__device__ __forceinline__ void cis_rev(float rev, float& c, float& s) {
    float f = rev - rintf(rev);                  // [-0.5, 0.5]
    float ang = 6.28318530717958647692f * f;     // [-pi, pi]
    float ss, cc;
    sincosf(ang, &ss, &cc);
    s = ss;
    c = cc;
}

// P[t][i][j][c] = csm[c,i,j] * im_t[i,j]; block 0 also zeroes d_out.
__global__ __launch_bounds__(256) void prep_kernel(
    const float* __restrict__ x, const float* __restrict__ csm,
    const float* __restrict__ flow, float* __restrict__ P,
    float* __restrict__ out, int out_size)
{
    int g = blockIdx.x * 256 + threadIdx.x;   // 0 .. NT*NPIX-1
    int t = g >> 14;
    int p = g & (NPIX - 1);
    int i = p >> 7, j = p & (N - 1);
    float f0 = flow[(p * 2 + 0) * NT + t];
    float f1 = flow[(p * 2 + 1) * NT + t];
    int si = (int)rintf((float)i + f0); si = min(max(si, 0), N - 1);
    int sj = (int)rintf((float)j + f1); sj = min(max(sj, 0), N - 1);
    float im = x[si * N + sj];
    float4 v;
    v.x = csm[0 * NPIX + p] * im;
    v.y = csm[1 * NPIX + p] * im;
    v.z = csm[2 * NPIX + p] * im;
    v.w = csm[3 * NPIX + p] * im;
    ((float4*)P)[g] = v;
    if (blockIdx.x == 0) {
        for (int k = threadIdx.x; k < out_size; k += 256) out[k] = 0.0f;
    }
}

// NDFT v5: wave = (j-half, m-quad); lane owns ONE j; 4 m per wave.
// Grid 2048: b -> ih = b&1 (i-half), t = (b>>1)&3, g = b>>3 (8 m-points).
// Wave w: jh = w&1 (j = jh*64 + lane), q = w>>1 (m = g*8 + q*4 + mm).
// Halves per-thread LDS reads vs R6 (4 ds_read_b128/chunk instead of 8).
__global__ __launch_bounds__(256, 4) void ndft5_kernel(
    const float* __restrict__ traj, const float4* __restrict__ P,
    float* __restrict__ out, int out_size)
{
    __shared__ float4 rows[2][512];   // [buf][4 rows x 128 j] = 16 KiB

    int b    = blockIdx.x;
    int ih   = b & 1;
    int t    = (b >> 1) & 3;
    int g    = b >> 3;                // 0..255
    int tid  = threadIdx.x;
    int lane = tid & 63;
    int w    = tid >> 6;
    int jh   = w & 1;
    int q    = w >> 1;
    int jcol = jh * 64 + lane;        // this lane's j
    int m0   = g * 8 + q * 4;         // 4 m's per wave

    const float4* Pt = P + t * NPIX + ih * (64 * N);   // this block's 64 rows

    // First chunk's staging loads issued before the sincos prologue.
    float4 sA = Pt[tid];
    float4 sB = Pt[tid + 256];

    float exr[4], exi[4], str_[4], sti_[4], eyr[4], eyi[4];
    float i0 = (float)(ih * 64);
#pragma unroll
    for (int mm = 0; mm < 4; ++mm) {
        int m  = m0 + mm;
        int sp = m >> 7;
        int r  = m & (N - 1);
        float kx = traj[((sp * N + r) * NT + t) * 2 + 0];
        float ky = traj[((sp * N + r) * NT + t) * 2 + 1];
        cis_rev(-kx * (i0 - 64.0f), exr[mm], exi[mm]);   // Ex at i = i0
        cis_rev(-kx, str_[mm], sti_[mm]);                // rotor step
        cis_rev(-ky * ((float)jcol - 64.0f), eyr[mm], eyi[mm]);
    }

    float ar[4][NC] = {}, ai[4][NC] = {};   // acc[m][c], complex

#define FMA_STEP(V)                                                        \
    {                                                                      \
        const float* f = (const float*)&(V);                               \
        _Pragma("unroll")                                                  \
        for (int mm = 0; mm < 4; ++mm) {                                   \
            _Pragma("unroll")                                              \
            for (int c = 0; c < NC; ++c) {                                 \
                ar[mm][c] = fmaf(exr[mm], f[c], ar[mm][c]);                \
                ai[mm][c] = fmaf(exi[mm], f[c], ai[mm][c]);                \
            }                                                              \
        }                                                                  \
        _Pragma("unroll")                                                  \
        for (int mm = 0; mm < 4; ++mm) {                                   \
            float er = exr[mm] * str_[mm] - exi[mm] * sti_[mm];            \
            float ei = fmaf(exr[mm], sti_[mm], exi[mm] * str_[mm]);        \
            exr[mm] = er; exi[mm] = ei;                                    \
        }                                                                  \
    }

    // Pipeline: stage chunk0, prefetch chunk1 into regs.
    rows[0][tid] = sA; rows[0][tid + 256] = sB;
    sA = Pt[512 + tid]; sB = Pt[512 + tid + 256];

    const int NCH = 16;   // 16 chunks x 4 rows = 64 i per block
    for (int ch = 0; ch < NCH; ++ch) {
        __syncthreads();
        int nb = (ch + 1) & 1;
        if (ch + 1 < NCH) { rows[nb][tid] = sA; rows[nb][tid + 256] = sB; }
        if (ch + 2 < NCH) {
            sA = Pt[(ch + 2) * 512 + tid];
            sB = Pt[(ch + 2) * 512 + tid + 256];
        }
        int cb = ch & 1;
#pragma unroll
        for (int s = 0; s < 4; ++s) {
            float4 v = rows[cb][s * 128 + jcol];
            FMA_STEP(v)
        }
    }
#undef FMA_STEP

    // Re{Ey * acc} for this lane's single j.
    float red[4][NC];
#pragma unroll
    for (int mm = 0; mm < 4; ++mm)
#pragma unroll
        for (int c = 0; c < NC; ++c)
            red[mm][c] = eyr[mm] * ar[mm][c] - eyi[mm] * ai[mm][c];

    // Butterfly reduce over 64 lanes (sums this wave's 64 j's).
#pragma unroll
    for (int d = 1; d < 64; d <<= 1)
#pragma unroll
        for (int mm = 0; mm < 4; ++mm)
#pragma unroll
            for (int c = 0; c < NC; ++c)
                red[mm][c] += __shfl_xor(red[mm][c], d, 64);

    if (lane == 0) {
#pragma unroll
        for (int mm = 0; mm < 4; ++mm) {
            int m  = m0 + mm;
            int sp = m >> 7;
            int r  = m & (N - 1);
#pragma unroll
            for (int c = 0; c < NC; ++c) {
                int qq = (r * NS + sp) * NC + c;   // C-order into [1][128][16][4]
                if (qq < out_size) atomicAdd(&out[qq], red[mm][c]);
            }
        }
    }
}

extern "C" void kernel_launch(void* const* d_in, const int* in_sizes, int n_in,
                              void* d_out, int out_size, void* d_ws, size_t ws_size,
                              hipStream_t stream) {
    const float* x    = (const float*)d_in[0];
    const float* traj = (const float*)d_in[1];
    const float* csm  = (const float*)d_in[2];
    // d_in[3] = dcf (unused by the reference)
    const float* flow = (const float*)d_in[4];
    float* out = (float*)d_out;
    float* P   = (float*)d_ws;

    prep_kernel<<<dim3(NT * NPIX / 256), dim3(256), 0, stream>>>(x, csm, flow, P, out, out_size);
    ndft5_kernel<<<dim3(2048), dim3(256), 0, stream>>>(traj, (const float4*)P, out, out_size);
}

// Round 8
// 74.120 us; speedup vs baseline: 1.4025x; 1.4025x over previous
//
#include <hip/hip_runtime.h>
#include <math.h>

#define N      128
#define NS     16
#define NC     4
#define NT     4
#define NPIX   (N * N)       // 16384
#define NJC    (N * NC)      // 512 columns (j*4+c)

typedef __attribute__((ext_vector_type(8))) short bf16x8;   // 8 bf16 = 4 VGPR
typedef __attribute__((ext_vector_type(4))) float f32x4;

// float -> bf16 bits, round-to-nearest-even
__device__ __forceinline__ short f2bf(float f) {
    union { float f; unsigned int u; } v; v.f = f;
    unsigned int r = (v.u + 0x7fffu + ((v.u >> 16) & 1u)) >> 16;
    return (short)r;
}

// cis(2*pi*rev) via libm sincosf on range-reduced radians.
__device__ __forceinline__ void cis_rev(float rev, float& c, float& s) {
    float f = rev - rintf(rev);
    float ang = 6.28318530717958647692f * f;
    float ss, cc;
    sincosf(ang, &ss, &cc);
    s = ss; c = cc;
}

// Pb[t][jc=j*4+c][i] = bf16(csm[c,i,j] * im_t[i,j])  (B-operand layout:
// contiguous in i so a lane's k-chunk is one 16B load). Block 0 zeroes out.
__global__ __launch_bounds__(256) void prep_kernel(
    const float* __restrict__ x, const float* __restrict__ csm,
    const float* __restrict__ flow, short* __restrict__ Pb,
    float* __restrict__ out, int out_size)
{
    int g = blockIdx.x * 256 + threadIdx.x;   // 0 .. NT*NPIX-1
    int t = g >> 14;
    int p = g & (NPIX - 1);
    int i = p >> 7, j = p & (N - 1);
    float f0 = flow[(p * 2 + 0) * NT + t];
    float f1 = flow[(p * 2 + 1) * NT + t];
    int si = (int)rintf((float)i + f0); si = min(max(si, 0), N - 1);
    int sj = (int)rintf((float)j + f1); sj = min(max(sj, 0), N - 1);
    float im = x[si * N + sj];
#pragma unroll
    for (int c = 0; c < NC; ++c) {
        float v = csm[c * NPIX + p] * im;
        Pb[((t * NJC) + j * 4 + c) * N + i] = f2bf(v);
    }
    if (blockIdx.x == 0) {
        for (int k = threadIdx.x; k < out_size; k += 256) out[k] = 0.0f;
    }
}

// MFMA NDFT: S[m,jc] = sum_i Ex[m,i] * P[i,jc] via 16x16x32 bf16 MFMA
// (2 chains: Exr, Exi), then out[m,c] += sum_j Re{Ey[m,j] * S}.
// Grid 256: b -> mtile = b>>1 (16 m), h = b&1 (jc half). Wave = t.
__global__ __launch_bounds__(256) void mfma_kernel(
    const float* __restrict__ traj, const short* __restrict__ Pb,
    float* __restrict__ out, int out_size)
{
    __shared__ float eyTab[NT][16][N][2];   // 64 KiB, one 16KB slab per wave/t

    int b     = blockIdx.x;
    int mtile = b >> 1;
    int h     = b & 1;
    int tid   = threadIdx.x;
    int lane  = tid & 63;
    int t     = tid >> 6;          // wave index = motion state
    int quad  = lane >> 4;
    int l15   = lane & 15;

    // ---- A fragments (in-register): Ex for m = mtile*16 + l15.
    // A layout: A[m = lane&15][k = quad*8 + e], k-step s adds s*32.
    int m  = mtile * 16 + l15;
    int sp = m >> 7, r = m & (N - 1);
    float kx = traj[((sp * N + r) * NT + t) * 2 + 0];

    bf16x8 ar[4], ai[4];
    {
        float stepr, stepi;
        cis_rev(-kx, stepr, stepi);
#pragma unroll
        for (int s = 0; s < 4; ++s) {
            float er, ei;
            cis_rev(-kx * (float)(s * 32 + quad * 8 - 64), er, ei);
#pragma unroll
            for (int e = 0; e < 8; ++e) {
                ar[s][e] = f2bf(er);
                ai[s][e] = f2bf(ei);
                float nr = er * stepr - ei * stepi;
                float ni = fmaf(er, stepi, ei * stepr);
                er = nr; ei = ni;
            }
        }
    }

    // ---- Ey table (wave-local slab): ey[m_rel][j] for this t.
    {
        int m2  = lane >> 2;                  // 0..15
        int mm  = mtile * 16 + m2;
        int sp2 = mm >> 7, r2 = mm & (N - 1);
        float ky = traj[((sp2 * N + r2) * NT + t) * 2 + 1];
        float sr, si_;
        cis_rev(-ky, sr, si_);
        int j0 = (lane & 3) * 32;
        float er, ei;
        cis_rev(-ky * (float)(j0 - 64), er, ei);
        for (int jj = 0; jj < 32; ++jj) {
            eyTab[t][m2][j0 + jj][0] = er;
            eyTab[t][m2][j0 + jj][1] = ei;
            float nr = er * sr - ei * si_;
            float ni = fmaf(er, si_, ei * sr);
            er = nr; ei = ni;
        }
    }
    __syncthreads();   // eyTab visible (also orders ds_write -> ds_read)

    // ---- Main loop over this half's 16 jc-tiles.
    const short* PbT = Pb + t * NJC * N;
    int jcb0 = h * 256;
    float partial[4] = {0.f, 0.f, 0.f, 0.f};

    // prefetch tile 0's B fragments: B[k=quad*8+e][n=l15] from Pb[jc][i]
    bf16x8 bpre[4];
#pragma unroll
    for (int s = 0; s < 4; ++s)
        bpre[s] = *(const bf16x8*)(PbT + (jcb0 + l15) * N + s * 32 + quad * 8);

    for (int nt = 0; nt < 16; ++nt) {
        bf16x8 bcur[4];
#pragma unroll
        for (int s = 0; s < 4; ++s) bcur[s] = bpre[s];
        if (nt + 1 < 16) {
            int jcn = jcb0 + (nt + 1) * 16 + l15;
#pragma unroll
            for (int s = 0; s < 4; ++s)
                bpre[s] = *(const bf16x8*)(PbT + jcn * N + s * 32 + quad * 8);
        }

        f32x4 accR = {0.f, 0.f, 0.f, 0.f};
        f32x4 accI = {0.f, 0.f, 0.f, 0.f};
#pragma unroll
        for (int s = 0; s < 4; ++s) {
            accR = __builtin_amdgcn_mfma_f32_16x16x32_bf16(ar[s], bcur[s], accR, 0, 0, 0);
            accI = __builtin_amdgcn_mfma_f32_16x16x32_bf16(ai[s], bcur[s], accI, 0, 0, 0);
        }

        // C/D layout: col = lane&15 (jc_rel), row = quad*4 + reg (m_rel).
        int jc = jcb0 + nt * 16 + l15;
        int j  = jc >> 2;
#pragma unroll
        for (int reg = 0; reg < 4; ++reg) {
            int mrel = quad * 4 + reg;
            float eyr = eyTab[t][mrel][j][0];
            float eyi = eyTab[t][mrel][j][1];
            partial[reg] = fmaf(eyr, accR[reg], partial[reg]);
            partial[reg] = fmaf(-eyi, accI[reg], partial[reg]);
        }
    }

    // ---- Reduce over the 4 j-subgroups (col bits 2,3 = lane bits 2,3).
#pragma unroll
    for (int reg = 0; reg < 4; ++reg) {
        partial[reg] += __shfl_xor(partial[reg], 4, 64);
        partial[reg] += __shfl_xor(partial[reg], 8, 64);
    }
    if ((lane & 12) == 0) {
        int c = lane & 3;
#pragma unroll
        for (int reg = 0; reg < 4; ++reg) {
            int mm  = mtile * 16 + quad * 4 + reg;
            int sp2 = mm >> 7, r2 = mm & (N - 1);
            int q = (r2 * NS + sp2) * NC + c;   // C-order into [1][128][16][4]
            if (q < out_size) atomicAdd(&out[q], partial[reg]);
        }
    }
}

extern "C" void kernel_launch(void* const* d_in, const int* in_sizes, int n_in,
                              void* d_out, int out_size, void* d_ws, size_t ws_size,
                              hipStream_t stream) {
    const float* x    = (const float*)d_in[0];
    const float* traj = (const float*)d_in[1];
    const float* csm  = (const float*)d_in[2];
    // d_in[3] = dcf (unused by the reference)
    const float* flow = (const float*)d_in[4];
    float* out = (float*)d_out;
    short* Pb  = (short*)d_ws;    // NT*512*128 bf16 = 512 KiB

    prep_kernel<<<dim3(NT * NPIX / 256), dim3(256), 0, stream>>>(x, csm, flow, Pb, out, out_size);
    mfma_kernel<<<dim3(256), dim3(256), 0, stream>>>(traj, Pb, out, out_size);
}